// Round 6
// baseline (314.211 us; speedup 1.0000x reference)
//
#include <hip/hip_runtime.h>
#include <stdint.h>

#define BB 512
#define TT 1000
#define CC 64
#define HH 128
#define TDA_F 150
#define NCLS 4
#define EPSV 1e-5f
#define NSEG 8
#define SEGLEN 125   // TT / NSEG
#define WARM 51      // uncounted warm-up; SEGLEN+WARM = 176 = 11 tiles of 16
#define CPAD 20      // cur row stride (floats): dense-optimal banks for b128

typedef _Float16 half8 __attribute__((ext_vector_type(8)));
typedef float floatx4 __attribute__((ext_vector_type(4)));

__device__ __forceinline__ half8 cvt8(const float4& a, const float4& b) {
  half8 r;
  r[0] = (_Float16)a.x; r[1] = (_Float16)a.y;
  r[2] = (_Float16)a.z; r[3] = (_Float16)a.w;
  r[4] = (_Float16)b.x; r[5] = (_Float16)b.y;
  r[6] = (_Float16)b.z; r[7] = (_Float16)b.w;
  return r;
}

// ---------------------------------------------------------------------------
// Fused current-GEMM (MFMA) + LIF scan. Grid: 512 b x 8 seg, single-wave
// blocks. Per 16-step tile: currents = kin_tile @ Wfc^T + b via
// mfma_f32_16x16x32_f16; A = kin (plain fp16, cvt per tile), B = Wfc split
// hi+lo ONCE pre-loop (2 MFMA per k-half -> 32/tile; B quantization exactly
// compensated, A rounding sigma~2e-4 -> rare +-1 spike flips, thr 19.28).
// R5 was latency-bound (MfmaUtil 17/VALU 29/HBM 15%, occ 18%): 1-deep
// prefetch < 900cyc HBM latency, and 64 scalar b32 LDS ops/tile. Now:
// 2-deep register prefetch; C-tiles stored h-major cur[128][20] with
// ds_write_b128 (pad-20 => dense-optimal banks both directions); LIF scan
// loads its 16 steps as 4x ds_read_b128 into REGISTERS, chain overlaps the
// next tile's MFMA. Single LDS buffer is safe: tile c-1 is fully read into
// regs before tile c's writes (same-wave lgkm ordering).
// ---------------------------------------------------------------------------
__global__ __launch_bounds__(64, 2) void snn_scan(
    const float* __restrict__ kin, const float* __restrict__ Wfc,
    const float* __restrict__ bfc, float* __restrict__ part)
{
  const int lane = threadIdx.x;
  const int q = lane >> 4;      // quad 0..3
  const int ml = lane & 15;     // m (=t row) for A / n (=h col) for B
  const int b = blockIdx.x >> 3;
  const int seg = blockIdx.x & 7;

  const int t0 = (seg == 0) ? 0 : SEGLEN * seg - WARM;
  const int ntiles = (seg == 0) ? 8 : 11;   // 128 or 176 steps
  const int lo = SEGLEN * seg;
  const int hi = lo + SEGLEN;

  // B fragments: W[n=ht*16+ml][k=kh*32+q*8+j], split fp16 hi + residual lo.
  // 32 half8 (128 regs) -- MFMA reads AGPR-demoted operands natively.
  half8 bh[8][2], bl[8][2];
  float bv[8];
#pragma unroll
  for (int ht = 0; ht < 8; ++ht) {
    bv[ht] = bfc[ht * 16 + ml];
#pragma unroll
    for (int kh = 0; kh < 2; ++kh) {
      const float* wp = Wfc + (ht * 16 + ml) * CC + kh * 32 + q * 8;
      float4 w0 = *(const float4*)(wp);
      float4 w1 = *(const float4*)(wp + 4);
      float wv[8] = {w0.x, w0.y, w0.z, w0.w, w1.x, w1.y, w1.z, w1.w};
      half8 h, l;
#pragma unroll
      for (int i = 0; i < 8; ++i) {
        _Float16 x = (_Float16)wv[i];
        h[i] = x;
        l[i] = (_Float16)(wv[i] - (float)x);
      }
      bh[ht][kh] = h;
      bl[ht][kh] = l;
    }
  }

  __shared__ float cur[HH * CPAD];  // 10,240 B

  // A loads: lane covers row t=t0+tile*16+ml, k-cols q*8 (+0 / +32).
  const float* ab = kin + ((size_t)b * TT + (t0 + ml)) * CC + q * 8;

  float4 p[2][4];
#pragma unroll
  for (int i = 0; i < 2; ++i) {
    const float* s = ab + i * 16 * CC;
    p[i][0] = *(const float4*)(s);
    p[i][1] = *(const float4*)(s + 4);
    p[i][2] = *(const float4*)(s + 32);
    p[i][3] = *(const float4*)(s + 36);
  }

  float mem0 = 0.f, mem1 = 0.f, cnt0 = 0.f, cnt1 = 0.f;

  for (int c = 0; c < ntiles; ++c) {
    // A frags for tile c (plain fp16).
    half8 a0 = cvt8(p[c & 1][0], p[c & 1][1]);
    half8 a1 = cvt8(p[c & 1][2], p[c & 1][3]);

    // Prefetch tile c+2 into the slot just freed (compiler tracks dep).
    if (c + 2 < ntiles) {
      const float* s = ab + (size_t)(c + 2) * 16 * CC;
      p[c & 1][0] = *(const float4*)(s);
      p[c & 1][1] = *(const float4*)(s + 4);
      p[c & 1][2] = *(const float4*)(s + 32);
      p[c & 1][3] = *(const float4*)(s + 36);
    }

    // MFMA tile c: 8 h-tiles x (2 k-halves x (hi+lo B)).
    floatx4 acc[8];
#pragma unroll
    for (int ht = 0; ht < 8; ++ht) {
      floatx4 a = {bv[ht], bv[ht], bv[ht], bv[ht]};  // bias folded in
      a = __builtin_amdgcn_mfma_f32_16x16x32_f16(a0, bl[ht][0], a, 0, 0, 0);
      a = __builtin_amdgcn_mfma_f32_16x16x32_f16(a0, bh[ht][0], a, 0, 0, 0);
      a = __builtin_amdgcn_mfma_f32_16x16x32_f16(a1, bl[ht][1], a, 0, 0, 0);
      a = __builtin_amdgcn_mfma_f32_16x16x32_f16(a1, bh[ht][1], a, 0, 0, 0);
      acc[ht] = a;
    }

    // Scan tile c-1 from LDS into registers; LIF chain overlaps MFMA above.
    if (c >= 1) {
      const float4* r0 = (const float4*)(cur + lane * CPAD);
      const float4* r1 = (const float4*)(cur + (lane + 64) * CPAD);
      float4 v0[4] = {r0[0], r0[1], r0[2], r0[3]};
      float4 v1[4] = {r1[0], r1[1], r1[2], r1[3]};
      const float* f0 = (const float*)v0;
      const float* f1 = (const float*)v1;
      const int tb = t0 + (c - 1) * 16;
#pragma unroll
      for (int s = 0; s < 16; ++s) {
        const int t = tb + s;
        const bool act = (t >= lo) && (t < hi);  // wave-uniform
        mem0 = fmaf(0.9f, mem0, f0[s]);
        mem1 = fmaf(0.9f, mem1, f1[s]);
        const bool s0 = (mem0 >= 1.0f);
        const bool s1 = (mem1 >= 1.0f);
        cnt0 += (act && s0) ? 1.0f : 0.0f;
        cnt1 += (act && s1) ? 1.0f : 0.0f;
        mem0 = s0 ? 0.0f : mem0;
        mem1 = s1 ? 0.0f : mem1;
      }
    }

    // Write tile c: D[row=t=q*4+r][col=h=ht*16+ml] -> cur[h][t], r contiguous
    // => one ds_write_b128 per ht. In-order after the reads above.
#pragma unroll
    for (int ht = 0; ht < 8; ++ht) {
      float4 st = {acc[ht][0], acc[ht][1], acc[ht][2], acc[ht][3]};
      *(float4*)(cur + (ht * 16 + ml) * CPAD + q * 4) = st;
    }
  }

  // Final tile's scan.
  {
    const float4* r0 = (const float4*)(cur + lane * CPAD);
    const float4* r1 = (const float4*)(cur + (lane + 64) * CPAD);
    float4 v0[4] = {r0[0], r0[1], r0[2], r0[3]};
    float4 v1[4] = {r1[0], r1[1], r1[2], r1[3]};
    const float* f0 = (const float*)v0;
    const float* f1 = (const float*)v1;
    const int tb = t0 + (ntiles - 1) * 16;
#pragma unroll
    for (int s = 0; s < 16; ++s) {
      const int t = tb + s;
      const bool act = (t >= lo) && (t < hi);
      mem0 = fmaf(0.9f, mem0, f0[s]);
      mem1 = fmaf(0.9f, mem1, f1[s]);
      const bool s0 = (mem0 >= 1.0f);
      const bool s1 = (mem1 >= 1.0f);
      cnt0 += (act && s0) ? 1.0f : 0.0f;
      cnt1 += (act && s1) ? 1.0f : 0.0f;
      mem0 = s0 ? 0.0f : mem0;
      mem1 = s1 ? 0.0f : mem1;
    }
  }

  float* pp = part + ((size_t)(seg * BB + b)) * HH;
  pp[lane] = cnt0;
  pp[lane + 64] = cnt1;
}

// ---------------------------------------------------------------------------
// Fused head: partial-count reduce + counts output + tda_net
// (150->64 relu ->64 relu) + fc1 (192->128). No atomics.
// ---------------------------------------------------------------------------
__global__ __launch_bounds__(HH) void fused_head(
    const float* __restrict__ part, const float* __restrict__ tda,
    const float* __restrict__ W1, const float* __restrict__ b1,
    const float* __restrict__ W2, const float* __restrict__ b2,
    const float* __restrict__ Wc1, const float* __restrict__ bc1,
    float* __restrict__ counts_out, float* __restrict__ hbuf)
{
  const int b = blockIdx.x, j = threadIdx.x;
  __shared__ float x[TDA_F];
  __shared__ float h1[64];
  __shared__ float f[HH + 64];

  float c = 0.0f;
#pragma unroll
  for (int s = 0; s < NSEG; ++s) c += part[((size_t)(s * BB + b)) * HH + j];
  counts_out[b * HH + j] = c;
  f[j] = c * (1.0f / TT);
  for (int i = j; i < TDA_F; i += HH) x[i] = tda[b * TDA_F + i];
  __syncthreads();
  if (j < 64) {
    float acc = b1[j];
    const float* wr = W1 + j * TDA_F;
#pragma unroll 5
    for (int i = 0; i < TDA_F; ++i) acc = fmaf(x[i], wr[i], acc);
    h1[j] = fmaxf(acc, 0.0f);
  }
  __syncthreads();
  if (j < 64) {
    float acc = b2[j];
    const float* wr = W2 + j * 64;
#pragma unroll
    for (int i = 0; i < 64; ++i) acc = fmaf(h1[i], wr[i], acc);
    f[HH + j] = fmaxf(acc, 0.0f);
  }
  __syncthreads();
  float acc = bc1[j];
  const float* wr = Wc1 + j * (HH + 64);
#pragma unroll 4
  for (int i = 0; i < HH + 64; ++i) acc = fmaf(f[i], wr[i], acc);
  hbuf[b * HH + j] = acc;
}

// ---------------------------------------------------------------------------
// BN (batch stats computed per-block from L2-resident hbuf -- removes the
// single-block bn_stats dispatch + its serialization) + relu + 128->4 GEMM.
// ---------------------------------------------------------------------------
__global__ __launch_bounds__(HH) void classifier2(
    const float* __restrict__ hbuf,
    const float* __restrict__ gamma, const float* __restrict__ beta,
    const float* __restrict__ Wc2, const float* __restrict__ bc2,
    float* __restrict__ out)
{
  const int b = blockIdx.x, j = threadIdx.x;
  float s0 = 0.f, q0 = 0.f, s1 = 0.f, q1 = 0.f;
  for (int r = 0; r < BB; r += 2) {
    float v0 = hbuf[r * HH + j];
    float v1 = hbuf[(r + 1) * HH + j];
    s0 += v0; q0 = fmaf(v0, v0, q0);
    s1 += v1; q1 = fmaf(v1, v1, q1);
  }
  const float mean = (s0 + s1) * (1.0f / BB);
  const float var = (q0 + q1) * (1.0f / BB) - mean * mean;
  const float rstd = rsqrtf(var + EPSV);

  float hn = (hbuf[b * HH + j] - mean) * rstd * gamma[j] + beta[j];
  hn = fmaxf(hn, 0.0f);

  __shared__ float red[NCLS][HH];
#pragma unroll
  for (int k = 0; k < NCLS; ++k) red[k][j] = hn * Wc2[k * HH + j];
  __syncthreads();
  for (int off = HH / 2; off >= 1; off >>= 1) {
    if (j < off) {
#pragma unroll
      for (int k = 0; k < NCLS; ++k) red[k][j] += red[k][j + off];
    }
    __syncthreads();
  }
  if (j < NCLS) out[b * NCLS + j] = red[j][0] + bc2[j];
}

// ---------------------------------------------------------------------------
extern "C" void kernel_launch(void* const* d_in, const int* in_sizes, int n_in,
                              void* d_out, int out_size, void* d_ws, size_t ws_size,
                              hipStream_t stream)
{
  const float* kin  = (const float*)d_in[0];   // [512,1000,64]
  const float* tda  = (const float*)d_in[1];   // [512,150]
  const float* Wfc  = (const float*)d_in[2];   // [128,64]
  const float* bfc  = (const float*)d_in[3];   // [128]
  const float* Wt1  = (const float*)d_in[4];   // [64,150]
  const float* bt1  = (const float*)d_in[5];   // [64]
  const float* Wt2  = (const float*)d_in[6];   // [64,64]
  const float* bt2  = (const float*)d_in[7];   // [64]
  const float* Wc1  = (const float*)d_in[8];   // [128,192]
  const float* bc1  = (const float*)d_in[9];   // [128]
  const float* gam  = (const float*)d_in[10];  // [128]
  const float* bet  = (const float*)d_in[11];  // [128]
  const float* Wc2  = (const float*)d_in[12];  // [4,128]
  const float* bc2  = (const float*)d_in[13];  // [4]

  float* out    = (float*)d_out;        // output 0: [512,4]
  float* counts = out + BB * NCLS;      // output 1: [512,128]

  float* part = (float*)d_ws;               // [8][512][128]  (2 MB)
  float* hbuf = part + NSEG * BB * HH;      // [512,128]

  snn_scan<<<BB * NSEG, 64, 0, stream>>>(kin, Wfc, bfc, part);
  fused_head<<<BB, HH, 0, stream>>>(part, tda, Wt1, bt1, Wt2, bt2,
                                    Wc1, bc1, counts, hbuf);
  classifier2<<<BB, HH, 0, stream>>>(hbuf, gam, bet, Wc2, bc2, out);
}